// Round 11
// baseline (144.297 us; speedup 1.0000x reference)
//
#include <hip/hip_runtime.h>
#include <math.h>

#define HN 8
#define POSN 16
#define SN 33
#define HALF_SN 16
#define CDIM 1024
#define LDIM 4096
#define BDIM 2
#define NTOK (BDIM * LDIM)

typedef unsigned short u16;
typedef short short8 __attribute__((ext_vector_type(8)));
typedef u16 u16x8 __attribute__((ext_vector_type(8)));
typedef unsigned int u32x4 __attribute__((ext_vector_type(4)));
typedef float f32x4 __attribute__((ext_vector_type(4)));
typedef float f32x2 __attribute__((ext_vector_type(2)));

// Precise versions (index-critical wave path ONLY)
__device__ __forceinline__ float sigf(float x) { return 1.0f / (1.0f + expf(-x)); }
__device__ __forceinline__ float siluf(float x) { return x / (1.0f + expf(-x)); }
// Fast versions (weight/epilogue paths: v_exp_f32 + v_rcp_f32)
__device__ __forceinline__ float frcp(float x) { return __builtin_amdgcn_rcpf(x); }
__device__ __forceinline__ float fexp(float x) { return __expf(x); }
__device__ __forceinline__ float fsig(float x) { return frcp(1.0f + fexp(-x)); }
__device__ __forceinline__ float fsilu(float x) { return x * fsig(x); }

__device__ __forceinline__ u16 f2b(float f) {
    union { float f; unsigned u; } v; v.f = f;
    unsigned r = v.u + 0x7fffu + ((v.u >> 16) & 1u);   // RNE
    return (u16)(r >> 16);
}
__device__ __forceinline__ float b2f(u16 v) {
    union { unsigned u; float f; } x; x.u = ((unsigned)v) << 16; return x.f;
}
__device__ __forceinline__ float u2f(unsigned u) {
    union { unsigned u; float f; } x; x.u = u; return x.f;
}
__device__ __forceinline__ void ld_lds16(const void* g, void* l) {
    __builtin_amdgcn_global_load_lds(
        (const __attribute__((address_space(1))) void*)g,
        (__attribute__((address_space(3))) void*)l, 16, 0, 0);
}

// ---------------------------------------------------------------------------
// PREP kernel: weight transcasts AND wave partial-sums in ONE launch.
//   [0,128)      query_w  -> bf16 [N][K]  N=128  K=1024
//   [128,384)    se1_w    -> bf16 [N][K]  N=256  K=1024
//   [384,640)    se2_w    -> bf16 [N][K]  N=1024 K=256
//   [640,1664)   out_w    -> bf16 [N][K]  N=1024 K=1024
//   [1664,2688)  wave partial: sl = p>>7, tg = p&127. Weight slice staged
//                directly from wave_w (transposed in LDS — pure copy reorder,
//                partials bit-identical to rounds 9/10). Fused xcast.
// No cross-block data dependency inside this kernel.
// ---------------------------------------------------------------------------
__global__ __launch_bounds__(256) void prep_kernel(
    const float* __restrict__ qw, const float* __restrict__ s1,
    const float* __restrict__ s2, const float* __restrict__ ow,
    const float* __restrict__ ww, const float* __restrict__ x,
    u16* __restrict__ oq, u16* __restrict__ o1,
    u16* __restrict__ o2, u16* __restrict__ oo,
    u16* __restrict__ xbf, float* __restrict__ part)
{
    const int bid = blockIdx.x;
    const int tid = threadIdx.x;

    if (bid < 1664) {      // ---- weight transcast ----
        const float* in; u16* out; int N, K, base;
        if      (bid < 128) { in = qw; out = oq; N = 128;  K = 1024; base = 0;   }
        else if (bid < 384) { in = s1; out = o1; N = 256;  K = 1024; base = 128; }
        else if (bid < 640) { in = s2; out = o2; N = 1024; K = 256;  base = 384; }
        else                { in = ow; out = oo; N = 1024; K = 1024; base = 640; }
        const int rel = bid - base, nx = N / 32;
        const int bn = (rel % nx) * 32, bk = (rel / nx) * 32;

        __shared__ float tile[32][33];
        const int tx = tid & 31, ty = tid >> 5;
        #pragma unroll
        for (int yy = ty; yy < 32; yy += 8)
            tile[yy][tx] = in[(size_t)(bk + yy) * N + bn + tx];
        __syncthreads();
        #pragma unroll
        for (int yy = ty; yy < 32; yy += 8)
            out[(size_t)(bn + yy) * K + bk + tx] = f2b(tile[tx][yy]);
        return;
    }

    // ---- wave partial sums (K-split) ----
    const int pid = bid - 1664;
    const int sl = pid >> 7;           // K slice 0..7
    const int tg = pid & 127;          // token group
    const int t0 = tg * 64;
    const int k0 = sl * 128;

    __shared__ float wsct[24][128];

    // stage weight slice from wave_w directly, transposing in LDS.
    // wave_w rows k0..k0+127 x 24 cols = 3072 contiguous floats.
    {
        const float* wsrc = ww + (size_t)k0 * 24;
        for (int i = tid; i < 768; i += 256) {
            float4 v = *(const float4*)(wsrc + i * 4);
            const int p = i * 4;
            const int k = p / 24, c0 = p % 24;   // 4|24: never crosses a row
            wsct[c0 + 0][k] = v.x; wsct[c0 + 1][k] = v.y;
            wsct[c0 + 2][k] = v.z; wsct[c0 + 3][k] = v.w;
        }
    }
    // fused xcast for this (64 tok x 128 k) tile — covers x exactly once
    for (int i = tid; i < 1024; i += 256) {
        const int r = i >> 4, c8 = (i & 15) * 8;
        const float* src = x + (size_t)(t0 + r) * CDIM + k0 + c8;
        float4 a = *(const float4*)(src);
        float4 b = *(const float4*)(src + 4);
        u16x8 o;
        o[0]=f2b(a.x); o[1]=f2b(a.y); o[2]=f2b(a.z); o[3]=f2b(a.w);
        o[4]=f2b(b.x); o[5]=f2b(b.y); o[6]=f2b(b.z); o[7]=f2b(b.w);
        *(u16x8*)(xbf + (size_t)(t0 + r) * CDIM + k0 + c8) = o;
    }
    __syncthreads();

    const int tok = tid & 63;
    const int cg  = tid >> 6;
    const int t = t0 + tok;
    const float* xr = x + (size_t)t * CDIM + k0;
    const int c0 = cg * 6;
    float a0=0.f, a1=0.f, a2=0.f, a3=0.f, a4=0.f, a5=0.f;

    #pragma unroll 4
    for (int kk = 0; kk < 128; kk += 4) {
        float4 xv = *(const float4*)(xr + kk);
        float4 w0 = *(const float4*)&wsct[c0 + 0][kk];
        float4 w1 = *(const float4*)&wsct[c0 + 1][kk];
        float4 w2 = *(const float4*)&wsct[c0 + 2][kk];
        float4 w3 = *(const float4*)&wsct[c0 + 3][kk];
        float4 w4 = *(const float4*)&wsct[c0 + 4][kk];
        float4 w5 = *(const float4*)&wsct[c0 + 5][kk];
        a0 += xv.x*w0.x; a0 += xv.y*w0.y; a0 += xv.z*w0.z; a0 += xv.w*w0.w;
        a1 += xv.x*w1.x; a1 += xv.y*w1.y; a1 += xv.z*w1.z; a1 += xv.w*w1.w;
        a2 += xv.x*w2.x; a2 += xv.y*w2.y; a2 += xv.z*w2.z; a2 += xv.w*w2.w;
        a3 += xv.x*w3.x; a3 += xv.y*w3.y; a3 += xv.z*w3.z; a3 += xv.w*w3.w;
        a4 += xv.x*w4.x; a4 += xv.y*w4.y; a4 += xv.z*w4.z; a4 += xv.w*w4.w;
        a5 += xv.x*w5.x; a5 += xv.y*w5.y; a5 += xv.z*w5.z; a5 += xv.w*w5.w;
    }
    float* pp = part + (size_t)sl * NTOK * 24 + (size_t)t * 24 + c0;
    pp[0]=a0; pp[1]=a1; pp[2]=a2; pp[3]=a3; pp[4]=a4; pp[5]=a5;
}

// ---------------------------------------------------------------------------
// bf16 MFMA GEMM, m97 structure + 2-phase prefetch + XCD swizzle (unchanged).
// CFG 0: 128x128 tile (MI=4 NJ=4)   CFG 2: 64x128 tile (MI=2 NJ=4)
// ---------------------------------------------------------------------------
template <int MODE, int CFG>
__global__ __launch_bounds__(256) void mfma_gemm(
    const u16* __restrict__ A, const u16* __restrict__ Bt,
    const float* __restrict__ bias, const u16* __restrict__ mulb,
    void* __restrict__ Cptr, int M, int N, int K)
{
    constexpr int BM  = (CFG == 0) ? 128 : 64;
    constexpr int MI  = (CFG == 0) ? 4 : 2;
    constexpr int NJ  = 4;
    constexpr int ACH = BM / 16;
    constexpr int NCH = ACH + 8;

    __shared__ u16 lds[2][(BM + 128) * 32];

    const int nwg = gridDim.x * gridDim.y;
    const int flat = blockIdx.y * gridDim.x + blockIdx.x;
    const int swz = (flat & 7) * (nwg >> 3) + (flat >> 3);   // nwg % 8 == 0
    const int bxi = swz / gridDim.y, byi = swz % gridDim.y;

    const int tid = threadIdx.x;
    const int bm = bxi * BM, bn = byi * 128;
    const int wid = tid >> 6, lane = tid & 63;
    const int wr = (CFG == 0) ? (wid >> 1) * 64 : (wid >> 1) * 32;
    const int wc = (wid & 1) * 64;
    const int fm = lane & 15;
    const int kg = (lane >> 4) * 8;
    const int lrow = lane >> 2;
    const int lk   = (lane & 3) * 8;

    f32x4 acc[MI][NJ];
    #pragma unroll
    for (int i = 0; i < MI; ++i)
        #pragma unroll
        for (int j = 0; j < NJ; ++j) acc[i][j] = (f32x4){0.f, 0.f, 0.f, 0.f};

    auto stage = [&](u16* dst, int k0s) {
        #pragma unroll
        for (int c = wid; c < NCH; c += 4) {
            const u16* gsrc = (c < ACH)
                ? A  + (size_t)(bm + c * 16 + lrow) * K + k0s + lk
                : Bt + (size_t)(bn + (c - ACH) * 16 + lrow) * K + k0s + lk;
            ld_lds16(gsrc, dst + c * 512 + lane * 8);
        }
    };

    stage(&lds[0][0], 0);
    __syncthreads();
    int cur = 0;
    for (int k0 = 0; k0 < K; k0 += 32) {
        const int k1 = (k0 + 32 < K) ? (k0 + 32) : k0;
        stage(&lds[cur ^ 1][0], k1);       // prefetch next K-step (in flight)
        short8 a[MI], b[NJ];
        #pragma unroll
        for (int i = 0; i < MI; ++i)
            a[i] = *(const short8*)&lds[cur][(wr + i * 16 + fm) * 32 + kg];
        #pragma unroll
        for (int j = 0; j < NJ; ++j)
            b[j] = *(const short8*)&lds[cur][(BM + wc + j * 16 + fm) * 32 + kg];
        #pragma unroll
        for (int i = 0; i < MI; ++i)
            #pragma unroll
            for (int j = 0; j < NJ; ++j)
                acc[i][j] = __builtin_amdgcn_mfma_f32_16x16x32_bf16(a[i], b[j], acc[i][j], 0, 0, 0);
        __syncthreads();
        cur ^= 1;
    }

    float* Cf = (float*)Cptr;
    u16* Cb = (u16*)Cptr;
    #pragma unroll
    for (int i = 0; i < MI; ++i) {
        const int row0 = bm + wr + i * 16 + (lane >> 4) * 4;
        #pragma unroll
        for (int j = 0; j < NJ; ++j) {
            const int col = bn + wc + j * 16 + fm;
            const float vb = (MODE == 3) ? 0.0f : bias[col];
            #pragma unroll
            for (int e = 0; e < 4; ++e) {
                const int row = row0 + e;
                float v = acc[i][j][e];
                if (MODE == 1) v = fsilu(v + vb);
                if (MODE == 2) v = fsig(v + vb) * b2f(mulb[(size_t)row * N + col]);
                if (MODE == 3) v = fsilu(v);
                if (MODE == 3) Cf[(size_t)row * N + col] = v;
                else           Cb[(size_t)row * N + col] = f2b(v);
            }
        }
    }
}

// ---------------------------------------------------------------------------
// Adaptive conv + fused wave fixup (fixup math verbatim — bit-identical
// sample_idx path). Gather now accumulates channel PAIRS in f32x2 so the
// compiler can emit v_pk_fma_f32 (per-channel order unchanged).
// ---------------------------------------------------------------------------
__global__ __launch_bounds__(256) void adaptconv_kernel(
    const u16* __restrict__ xbf, const float* __restrict__ key_w,
    const u16* __restrict__ qb, const float* __restrict__ part,
    const float* __restrict__ wave_b, u16* __restrict__ out)
{
    const int bid = blockIdx.x;
    const int swz = (bid & 7) * (NTOK / 16) + (bid >> 3);   // XCD-chunked
    const int sub = threadIdx.x >> 7, lt = threadIdx.x & 127;
    const int t = swz * 2 + sub;
    const int b = t / LDIM, l = t % LDIM;
    const int h = lt >> 4;
    const int li = lt & 15;

    __shared__ float qs[2][HN][17];
    __shared__ float kw[POSN];
    __shared__ float wpre[2][24];
    __shared__ float psh_s[2][HN];
    __shared__ float favg_s[2], pavg_s[2];
    __shared__ float fr[2][HN], dc[2][HN];
    __shared__ int   boff[2][SN];
    __shared__ float msk[2][SN];
    __shared__ float vsh[2][HN][17];
    __shared__ float esh[2][HN][17];
    __shared__ float wgt[2][HN][SN];

    qs[sub][lt >> 4][lt & 15] = b2f(qb[(size_t)t * 128 + lt]);
    if (threadIdx.x < POSN) kw[threadIdx.x] = key_w[threadIdx.x];

    // ---- fused wave fixup: bias + partials in fixed slice order ----
    if (lt < 24) {
        float s = wave_b[lt];
        #pragma unroll
        for (int sl = 0; sl < 8; ++sl)
            s += part[(size_t)sl * NTOK * 24 + (size_t)t * 24 + lt];
        wpre[sub][lt] = siluf(s);               // identical fn sequence
    }
    __syncthreads();
    if (lt < HN) {
        float f = sigf(wpre[sub][lt])      * 15.0f + 1.0f;
        float p = tanhf(wpre[sub][8 + lt]) * 16.0f;
        float d = sigf(wpre[sub][16 + lt]) * 9.5f + 0.5f;
        fr[sub][lt] = f; dc[sub][lt] = d; psh_s[sub][lt] = p;
    }
    __syncthreads();
    if (lt == 0) {
        float fa = 0.f, pa = 0.f;
        for (int hh = 0; hh < HN; ++hh) { fa += fr[sub][hh]; pa += psh_s[sub][hh]; }
        favg_s[sub] = fa * 0.125f; pavg_s[sub] = pa * 0.125f;
    }
    __syncthreads();
    if (lt < SN) {
        // ---- index path: IDENTICAL expressions to rounds 2-10 ----
        float fa = favg_s[sub], pa = pavg_s[sub];
        float sp = (float)l + (float)(lt - HALF_SN) * fa + pa;
        bool v = (sp >= 0.0f) && (sp < (float)LDIM);
        int si = (int)sp;
        si = min(max(si, 0), LDIM - 1);
        boff[sub][lt] = si * (CDIM * 2);
        msk[sub][lt] = v ? 1.0f : 0.0f;
    }
    __syncthreads();

    {
        const float fh = fr[sub][h];
        const float rdci = frcp(fmaxf(dc[sub][h], 0.1f));
        for (int ds = li; ds < 17; ds += 16) {
            float rel = (float)ds * fh;
            float acc = 0.0f;
            #pragma unroll
            for (int p = 0; p < POSN; ++p)
                acc += qs[sub][h][p] * fsilu(rel * kw[p]);
            vsh[sub][h][ds] = 0.25f * acc;
            esh[sub][h][ds] = fexp(-rel * rdci);
        }
    }
    __syncthreads();

    {
        const int ns = (li == 0) ? 3 : 2;
        int   sI[3] = { li, li + 16, 32 };
        float lg[3];
        #pragma unroll
        for (int k = 0; k < 3; ++k) {
            if (k < ns) {
                const int s = sI[k], ds = abs(s - 16);
                lg[k] = (msk[sub][s] != 0.0f) ? vsh[sub][h][ds] : -1e30f;
            } else lg[k] = -3.4e38f;
        }
        float m = fmaxf(lg[0], fmaxf(lg[1], lg[2]));
        #pragma unroll
        for (int d = 1; d < 16; d <<= 1) m = fmaxf(m, __shfl_xor(m, d));

        float e[3]; float ssum = 0.0f;
        #pragma unroll
        for (int k = 0; k < 3; ++k) {
            e[k] = (k < ns) ? fexp(lg[k] - m) : 0.0f;
            ssum += e[k];
        }
        #pragma unroll
        for (int d = 1; d < 16; d <<= 1) ssum += __shfl_xor(ssum, d);

        const float rss = frcp(ssum);
        float wv[3]; float wsum = 0.0f;
        #pragma unroll
        for (int k = 0; k < 3; ++k) {
            if (k < ns) {
                const int s = sI[k], ds = abs(s - 16);
                wv[k] = e[k] * rss * esh[sub][h][ds] * msk[sub][s];
            } else wv[k] = 0.0f;
            wsum += wv[k];
        }
        #pragma unroll
        for (int d = 1; d < 16; d <<= 1) wsum += __shfl_xor(wsum, d);

        const float inv = frcp(wsum + 1e-8f);
        #pragma unroll
        for (int k = 0; k < 3; ++k)
            if (k < ns) wgt[sub][h][sI[k]] = wv[k] * inv;
    }
    __syncthreads();

    const char* xbB = (const char*)(xbf + (size_t)b * LDIM * CDIM);
    const int cbyte = lt * 16;
    f32x2 ac0 = {0.f, 0.f}, ac1 = {0.f, 0.f}, ac2 = {0.f, 0.f}, ac3 = {0.f, 0.f};

    // packed: {lo,hi} channel pair per u32; per-channel sum order unchanged
    #define GFMA(V, W) do { \
        f32x2 ww_ = { (W), (W) }; \
        f32x2 p0 = { u2f((V)[0] << 16), u2f((V)[0] & 0xffff0000u) }; \
        f32x2 p1 = { u2f((V)[1] << 16), u2f((V)[1] & 0xffff0000u) }; \
        f32x2 p2 = { u2f((V)[2] << 16), u2f((V)[2] & 0xffff0000u) }; \
        f32x2 p3 = { u2f((V)[3] << 16), u2f((V)[3] & 0xffff0000u) }; \
        ac0 += ww_ * p0; ac1 += ww_ * p1; ac2 += ww_ * p2; ac3 += ww_ * p3; } while (0)

    int s = 0;
    for (; s + 4 <= SN; s += 4) {
        u32x4 v0 = *(const u32x4*)(xbB + boff[sub][s]     + cbyte);
        u32x4 v1 = *(const u32x4*)(xbB + boff[sub][s + 1] + cbyte);
        u32x4 v2 = *(const u32x4*)(xbB + boff[sub][s + 2] + cbyte);
        u32x4 v3 = *(const u32x4*)(xbB + boff[sub][s + 3] + cbyte);
        float w0 = wgt[sub][h][s],     w1 = wgt[sub][h][s + 1];
        float w2 = wgt[sub][h][s + 2], w3 = wgt[sub][h][s + 3];
        GFMA(v0, w0); GFMA(v1, w1); GFMA(v2, w2); GFMA(v3, w3);
    }
    for (; s < SN; ++s) {
        u32x4 v = *(const u32x4*)(xbB + boff[sub][s] + cbyte);
        float w = wgt[sub][h][s];
        GFMA(v, w);
    }
    #undef GFMA

    u16x8 o;
    o[0]=f2b(ac0[0]); o[1]=f2b(ac0[1]); o[2]=f2b(ac1[0]); o[3]=f2b(ac1[1]);
    o[4]=f2b(ac2[0]); o[5]=f2b(ac2[1]); o[6]=f2b(ac3[0]); o[7]=f2b(ac3[1]);
    *(u16x8*)(out + (size_t)t * CDIM + lt * 8) = o;
}

// ---------------------------------------------------------------------------
extern "C" void kernel_launch(void* const* d_in, const int* in_sizes, int n_in,
                              void* d_out, int out_size, void* d_ws, size_t ws_size,
                              hipStream_t stream)
{
    const float* x       = (const float*)d_in[0];
    const float* wave_w  = (const float*)d_in[1];
    const float* wave_b  = (const float*)d_in[2];
    const float* query_w = (const float*)d_in[3];
    const float* query_b = (const float*)d_in[4];
    const float* key_w   = (const float*)d_in[5];
    const float* out_w   = (const float*)d_in[6];
    const float* se1_w   = (const float*)d_in[7];
    const float* se1_b   = (const float*)d_in[8];
    const float* se2_w   = (const float*)d_in[9];
    const float* se2_b   = (const float*)d_in[10];

    char* wsb = (char*)d_ws;
    u16* q_bf    = (u16*)wsb;           wsb += (size_t)NTOK * 128 * 2;
    u16* x_bf    = (u16*)wsb;           wsb += (size_t)NTOK * CDIM * 2;
    u16* conv_bf = (u16*)wsb;           wsb += (size_t)NTOK * CDIM * 2;
    u16* tmp1_bf = (u16*)wsb;           wsb += (size_t)NTOK * 256 * 2;
    u16* g_bf    = (u16*)wsb;           wsb += (size_t)NTOK * CDIM * 2;
    u16* qw_bf   = (u16*)wsb;           wsb += (size_t)128 * CDIM * 2;
    u16* se1w_bf = (u16*)wsb;           wsb += (size_t)256 * CDIM * 2;
    u16* se2w_bf = (u16*)wsb;           wsb += (size_t)CDIM * 256 * 2;
    u16* outw_bf = (u16*)wsb;           wsb += (size_t)CDIM * CDIM * 2;
    float* part  = (float*)wsb;         wsb += (size_t)8 * NTOK * 24 * 4;

    // Weight transcasts + wave K-split partials (+fused xcast) in ONE launch
    prep_kernel<<<2688, 256, 0, stream>>>(
        query_w, se1_w, se2_w, out_w, wave_w, x,
        qw_bf, se1w_bf, se2w_bf, outw_bf, x_bf, part);

    // QPROJ: silu(x @ query_w + b) -> q (bf16).  64x128 tile
    mfma_gemm<1, 2><<<dim3(NTOK / 64, 1), 256, 0, stream>>>(
        x_bf, qw_bf, query_b, nullptr, q_bf, NTOK, 128, CDIM);

    // Adaptive conv (+fused wave fixup) -> conv (bf16)
    adaptconv_kernel<<<NTOK / 2, 256, 0, stream>>>(
        x_bf, key_w, q_bf, part, wave_b, conv_bf);

    // SE1: silu(conv @ se1_w + b) -> tmp1 (bf16).  64x128 tile
    mfma_gemm<1, 2><<<dim3(NTOK / 64, 256 / 128), 256, 0, stream>>>(
        conv_bf, se1w_bf, se1_b, nullptr, tmp1_bf, NTOK, 256, CDIM);

    // SE2: sigmoid(tmp1 @ se2_w + b) * conv -> g (bf16)
    mfma_gemm<2, 0><<<dim3(NTOK / 128, CDIM / 128), 256, 0, stream>>>(
        tmp1_bf, se2w_bf, se2_b, conv_bf, g_bf, NTOK, CDIM, 256);

    // OUT: silu(g @ out_w) -> d_out (f32)
    mfma_gemm<3, 0><<<dim3(NTOK / 128, CDIM / 128), 256, 0, stream>>>(
        g_bf, outw_bf, nullptr, nullptr, d_out, NTOK, CDIM, CDIM);
}

// Round 12
// 134.691 us; speedup vs baseline: 1.0713x; 1.0713x over previous
//
#include <hip/hip_runtime.h>
#include <math.h>

#define HN 8
#define POSN 16
#define SN 33
#define HALF_SN 16
#define CDIM 1024
#define LDIM 4096
#define BDIM 2
#define NTOK (BDIM * LDIM)

typedef unsigned short u16;
typedef short short8 __attribute__((ext_vector_type(8)));
typedef u16 u16x8 __attribute__((ext_vector_type(8)));
typedef unsigned int u32x4 __attribute__((ext_vector_type(4)));
typedef float f32x4 __attribute__((ext_vector_type(4)));

// Precise versions (index-critical wave path ONLY)
__device__ __forceinline__ float sigf(float x) { return 1.0f / (1.0f + expf(-x)); }
__device__ __forceinline__ float siluf(float x) { return x / (1.0f + expf(-x)); }
// Fast versions (weight/epilogue paths: v_exp_f32 + v_rcp_f32)
__device__ __forceinline__ float frcp(float x) { return __builtin_amdgcn_rcpf(x); }
__device__ __forceinline__ float fexp(float x) { return __expf(x); }
__device__ __forceinline__ float fsig(float x) { return frcp(1.0f + fexp(-x)); }
__device__ __forceinline__ float fsilu(float x) { return x * fsig(x); }

__device__ __forceinline__ u16 f2b(float f) {
    union { float f; unsigned u; } v; v.f = f;
    unsigned r = v.u + 0x7fffu + ((v.u >> 16) & 1u);   // RNE
    return (u16)(r >> 16);
}
__device__ __forceinline__ float b2f(u16 v) {
    union { unsigned u; float f; } x; x.u = ((unsigned)v) << 16; return x.f;
}
__device__ __forceinline__ float u2f(unsigned u) {
    union { unsigned u; float f; } x; x.u = u; return x.f;
}
__device__ __forceinline__ void ld_lds16(const void* g, void* l) {
    __builtin_amdgcn_global_load_lds(
        (const __attribute__((address_space(1))) void*)g,
        (__attribute__((address_space(3))) void*)l, 16, 0, 0);
}

// ---------------------------------------------------------------------------
// All weight preps in ONE launch (round-10 configuration).
//   [0,128)      query_w  -> bf16 [N][K]  N=128  K=1024
//   [128,384)    se1_w    -> bf16 [N][K]  N=256  K=1024
//   [384,640)    se2_w    -> bf16 [N][K]  N=1024 K=256
//   [640,1664)   out_w    -> bf16 [N][K]  N=1024 K=1024
//   [1664,1760)  wave_w   -> fp32 transposed [24][1024]  (exact copy)
// ---------------------------------------------------------------------------
__global__ __launch_bounds__(256) void transcast_all(
    const float* __restrict__ qw, const float* __restrict__ s1,
    const float* __restrict__ s2, const float* __restrict__ ow,
    const float* __restrict__ ww,
    u16* __restrict__ oq, u16* __restrict__ o1,
    u16* __restrict__ o2, u16* __restrict__ oo,
    float* __restrict__ owT)
{
    const int bid = blockIdx.x;
    if (bid >= 1664) {   // wave_w fp32 transpose
        const int idx = (bid - 1664) * 256 + threadIdx.x;
        const int c = idx >> 10, k = idx & 1023;
        owT[idx] = ww[k * 24 + c];
        return;
    }
    const float* in; u16* out; int N, K, base;
    if      (bid < 128) { in = qw; out = oq; N = 128;  K = 1024; base = 0;   }
    else if (bid < 384) { in = s1; out = o1; N = 256;  K = 1024; base = 128; }
    else if (bid < 640) { in = s2; out = o2; N = 1024; K = 256;  base = 384; }
    else                { in = ow; out = oo; N = 1024; K = 1024; base = 640; }
    const int rel = bid - base, nx = N / 32;
    const int bn = (rel % nx) * 32, bk = (rel / nx) * 32;

    __shared__ float tile[32][33];
    const int tx = threadIdx.x & 31, ty = threadIdx.x >> 5;
    #pragma unroll
    for (int yy = ty; yy < 32; yy += 8)
        tile[yy][tx] = in[(size_t)(bk + yy) * N + bn + tx];
    __syncthreads();
    #pragma unroll
    for (int yy = ty; yy < 32; yy += 8)
        out[(size_t)(bn + yy) * K + bk + tx] = f2b(tile[tx][yy]);
}

// ---------------------------------------------------------------------------
// Wave projection stage 1: K-split partial sums (round-10 configuration,
// wwT-sourced staging — conflict-free, bit-identical partials).
// ---------------------------------------------------------------------------
__global__ __launch_bounds__(256) void wave_partial(
    const float* __restrict__ x, const float* __restrict__ wwT,
    u16* __restrict__ xbf, float* __restrict__ part)
{
    const int bid = blockIdx.x;
    const int sl = bid >> 7;           // K slice 0..7
    const int tg = bid & 127;          // token group
    const int tid = threadIdx.x;
    const int t0 = tg * 64;
    const int k0 = sl * 128;

    __shared__ float wsct[24][128];

    for (int i = tid; i < 768; i += 256) {
        const int c = i >> 5, k4 = (i & 31) * 4;
        *(float4*)&wsct[c][k4] = *(const float4*)(wwT + (size_t)c * 1024 + k0 + k4);
    }
    for (int i = tid; i < 1024; i += 256) {
        const int r = i >> 4, c8 = (i & 15) * 8;
        const float* src = x + (size_t)(t0 + r) * CDIM + k0 + c8;
        float4 a = *(const float4*)(src);
        float4 b = *(const float4*)(src + 4);
        u16x8 o;
        o[0]=f2b(a.x); o[1]=f2b(a.y); o[2]=f2b(a.z); o[3]=f2b(a.w);
        o[4]=f2b(b.x); o[5]=f2b(b.y); o[6]=f2b(b.z); o[7]=f2b(b.w);
        *(u16x8*)(xbf + (size_t)(t0 + r) * CDIM + k0 + c8) = o;
    }
    __syncthreads();

    const int tok = tid & 63;
    const int cg  = tid >> 6;
    const int t = t0 + tok;
    const float* xr = x + (size_t)t * CDIM + k0;
    const int c0 = cg * 6;
    float a0=0.f, a1=0.f, a2=0.f, a3=0.f, a4=0.f, a5=0.f;

    #pragma unroll 4
    for (int kk = 0; kk < 128; kk += 4) {
        float4 xv = *(const float4*)(xr + kk);
        float4 w0 = *(const float4*)&wsct[c0 + 0][kk];
        float4 w1 = *(const float4*)&wsct[c0 + 1][kk];
        float4 w2 = *(const float4*)&wsct[c0 + 2][kk];
        float4 w3 = *(const float4*)&wsct[c0 + 3][kk];
        float4 w4 = *(const float4*)&wsct[c0 + 4][kk];
        float4 w5 = *(const float4*)&wsct[c0 + 5][kk];
        a0 += xv.x*w0.x; a0 += xv.y*w0.y; a0 += xv.z*w0.z; a0 += xv.w*w0.w;
        a1 += xv.x*w1.x; a1 += xv.y*w1.y; a1 += xv.z*w1.z; a1 += xv.w*w1.w;
        a2 += xv.x*w2.x; a2 += xv.y*w2.y; a2 += xv.z*w2.z; a2 += xv.w*w2.w;
        a3 += xv.x*w3.x; a3 += xv.y*w3.y; a3 += xv.z*w3.z; a3 += xv.w*w3.w;
        a4 += xv.x*w4.x; a4 += xv.y*w4.y; a4 += xv.z*w4.z; a4 += xv.w*w4.w;
        a5 += xv.x*w5.x; a5 += xv.y*w5.y; a5 += xv.z*w5.z; a5 += xv.w*w5.w;
    }
    float* pp = part + (size_t)sl * NTOK * 24 + (size_t)t * 24 + c0;
    pp[0]=a0; pp[1]=a1; pp[2]=a2; pp[3]=a3; pp[4]=a4; pp[5]=a5;
}

// ---------------------------------------------------------------------------
// bf16 MFMA GEMM, m97 structure + 2-phase prefetch + XCD swizzle (unchanged).
// CFG 0: 128x128 tile (MI=4 NJ=4)   CFG 2: 64x128 tile (MI=2 NJ=4)
// ---------------------------------------------------------------------------
template <int MODE, int CFG>
__global__ __launch_bounds__(256) void mfma_gemm(
    const u16* __restrict__ A, const u16* __restrict__ Bt,
    const float* __restrict__ bias, const u16* __restrict__ mulb,
    void* __restrict__ Cptr, int M, int N, int K)
{
    constexpr int BM  = (CFG == 0) ? 128 : 64;
    constexpr int MI  = (CFG == 0) ? 4 : 2;
    constexpr int NJ  = 4;
    constexpr int ACH = BM / 16;
    constexpr int NCH = ACH + 8;

    __shared__ u16 lds[2][(BM + 128) * 32];

    const int nwg = gridDim.x * gridDim.y;
    const int flat = blockIdx.y * gridDim.x + blockIdx.x;
    const int swz = (flat & 7) * (nwg >> 3) + (flat >> 3);   // nwg % 8 == 0
    const int bxi = swz / gridDim.y, byi = swz % gridDim.y;

    const int tid = threadIdx.x;
    const int bm = bxi * BM, bn = byi * 128;
    const int wid = tid >> 6, lane = tid & 63;
    const int wr = (CFG == 0) ? (wid >> 1) * 64 : (wid >> 1) * 32;
    const int wc = (wid & 1) * 64;
    const int fm = lane & 15;
    const int kg = (lane >> 4) * 8;
    const int lrow = lane >> 2;
    const int lk   = (lane & 3) * 8;

    f32x4 acc[MI][NJ];
    #pragma unroll
    for (int i = 0; i < MI; ++i)
        #pragma unroll
        for (int j = 0; j < NJ; ++j) acc[i][j] = (f32x4){0.f, 0.f, 0.f, 0.f};

    auto stage = [&](u16* dst, int k0s) {
        #pragma unroll
        for (int c = wid; c < NCH; c += 4) {
            const u16* gsrc = (c < ACH)
                ? A  + (size_t)(bm + c * 16 + lrow) * K + k0s + lk
                : Bt + (size_t)(bn + (c - ACH) * 16 + lrow) * K + k0s + lk;
            ld_lds16(gsrc, dst + c * 512 + lane * 8);
        }
    };

    stage(&lds[0][0], 0);
    __syncthreads();
    int cur = 0;
    for (int k0 = 0; k0 < K; k0 += 32) {
        const int k1 = (k0 + 32 < K) ? (k0 + 32) : k0;
        stage(&lds[cur ^ 1][0], k1);       // prefetch next K-step (in flight)
        short8 a[MI], b[NJ];
        #pragma unroll
        for (int i = 0; i < MI; ++i)
            a[i] = *(const short8*)&lds[cur][(wr + i * 16 + fm) * 32 + kg];
        #pragma unroll
        for (int j = 0; j < NJ; ++j)
            b[j] = *(const short8*)&lds[cur][(BM + wc + j * 16 + fm) * 32 + kg];
        #pragma unroll
        for (int i = 0; i < MI; ++i)
            #pragma unroll
            for (int j = 0; j < NJ; ++j)
                acc[i][j] = __builtin_amdgcn_mfma_f32_16x16x32_bf16(a[i], b[j], acc[i][j], 0, 0, 0);
        __syncthreads();
        cur ^= 1;
    }

    float* Cf = (float*)Cptr;
    u16* Cb = (u16*)Cptr;
    #pragma unroll
    for (int i = 0; i < MI; ++i) {
        const int row0 = bm + wr + i * 16 + (lane >> 4) * 4;
        #pragma unroll
        for (int j = 0; j < NJ; ++j) {
            const int col = bn + wc + j * 16 + fm;
            const float vb = (MODE == 3) ? 0.0f : bias[col];
            #pragma unroll
            for (int e = 0; e < 4; ++e) {
                const int row = row0 + e;
                float v = acc[i][j][e];
                if (MODE == 1) v = fsilu(v + vb);
                if (MODE == 2) v = fsig(v + vb) * b2f(mulb[(size_t)row * N + col]);
                if (MODE == 3) v = fsilu(v);
                if (MODE == 3) Cf[(size_t)row * N + col] = v;
                else           Cb[(size_t)row * N + col] = f2b(v);
            }
        }
    }
}

// ---------------------------------------------------------------------------
// Adaptive conv + fused wave fixup (round-10 configuration; fixup math
// verbatim — bit-identical sample_idx path; scalar-unpack gather).
// ---------------------------------------------------------------------------
__global__ __launch_bounds__(256) void adaptconv_kernel(
    const u16* __restrict__ xbf, const float* __restrict__ key_w,
    const u16* __restrict__ qb, const float* __restrict__ part,
    const float* __restrict__ wave_b, u16* __restrict__ out)
{
    const int bid = blockIdx.x;
    const int swz = (bid & 7) * (NTOK / 16) + (bid >> 3);   // XCD-chunked
    const int sub = threadIdx.x >> 7, lt = threadIdx.x & 127;
    const int t = swz * 2 + sub;
    const int b = t / LDIM, l = t % LDIM;
    const int h = lt >> 4;
    const int li = lt & 15;

    __shared__ float qs[2][HN][17];
    __shared__ float kw[POSN];
    __shared__ float wpre[2][24];
    __shared__ float psh_s[2][HN];
    __shared__ float favg_s[2], pavg_s[2];
    __shared__ float fr[2][HN], dc[2][HN];
    __shared__ int   boff[2][SN];
    __shared__ float msk[2][SN];
    __shared__ float vsh[2][HN][17];
    __shared__ float esh[2][HN][17];
    __shared__ float wgt[2][HN][SN];

    qs[sub][lt >> 4][lt & 15] = b2f(qb[(size_t)t * 128 + lt]);
    if (threadIdx.x < POSN) kw[threadIdx.x] = key_w[threadIdx.x];

    // ---- fused wave fixup: bias + partials in fixed slice order ----
    if (lt < 24) {
        float s = wave_b[lt];
        #pragma unroll
        for (int sl = 0; sl < 8; ++sl)
            s += part[(size_t)sl * NTOK * 24 + (size_t)t * 24 + lt];
        wpre[sub][lt] = siluf(s);               // identical fn sequence
    }
    __syncthreads();
    if (lt < HN) {
        float f = sigf(wpre[sub][lt])      * 15.0f + 1.0f;
        float p = tanhf(wpre[sub][8 + lt]) * 16.0f;
        float d = sigf(wpre[sub][16 + lt]) * 9.5f + 0.5f;
        fr[sub][lt] = f; dc[sub][lt] = d; psh_s[sub][lt] = p;
    }
    __syncthreads();
    if (lt == 0) {
        float fa = 0.f, pa = 0.f;
        for (int hh = 0; hh < HN; ++hh) { fa += fr[sub][hh]; pa += psh_s[sub][hh]; }
        favg_s[sub] = fa * 0.125f; pavg_s[sub] = pa * 0.125f;
    }
    __syncthreads();
    if (lt < SN) {
        // ---- index path: IDENTICAL expressions to rounds 2-11 ----
        float fa = favg_s[sub], pa = pavg_s[sub];
        float sp = (float)l + (float)(lt - HALF_SN) * fa + pa;
        bool v = (sp >= 0.0f) && (sp < (float)LDIM);
        int si = (int)sp;
        si = min(max(si, 0), LDIM - 1);
        boff[sub][lt] = si * (CDIM * 2);
        msk[sub][lt] = v ? 1.0f : 0.0f;
    }
    __syncthreads();

    {
        const float fh = fr[sub][h];
        const float rdci = frcp(fmaxf(dc[sub][h], 0.1f));
        for (int ds = li; ds < 17; ds += 16) {
            float rel = (float)ds * fh;
            float acc = 0.0f;
            #pragma unroll
            for (int p = 0; p < POSN; ++p)
                acc += qs[sub][h][p] * fsilu(rel * kw[p]);
            vsh[sub][h][ds] = 0.25f * acc;
            esh[sub][h][ds] = fexp(-rel * rdci);
        }
    }
    __syncthreads();

    {
        const int ns = (li == 0) ? 3 : 2;
        int   sI[3] = { li, li + 16, 32 };
        float lg[3];
        #pragma unroll
        for (int k = 0; k < 3; ++k) {
            if (k < ns) {
                const int s = sI[k], ds = abs(s - 16);
                lg[k] = (msk[sub][s] != 0.0f) ? vsh[sub][h][ds] : -1e30f;
            } else lg[k] = -3.4e38f;
        }
        float m = fmaxf(lg[0], fmaxf(lg[1], lg[2]));
        #pragma unroll
        for (int d = 1; d < 16; d <<= 1) m = fmaxf(m, __shfl_xor(m, d));

        float e[3]; float ssum = 0.0f;
        #pragma unroll
        for (int k = 0; k < 3; ++k) {
            e[k] = (k < ns) ? fexp(lg[k] - m) : 0.0f;
            ssum += e[k];
        }
        #pragma unroll
        for (int d = 1; d < 16; d <<= 1) ssum += __shfl_xor(ssum, d);

        const float rss = frcp(ssum);
        float wv[3]; float wsum = 0.0f;
        #pragma unroll
        for (int k = 0; k < 3; ++k) {
            if (k < ns) {
                const int s = sI[k], ds = abs(s - 16);
                wv[k] = e[k] * rss * esh[sub][h][ds] * msk[sub][s];
            } else wv[k] = 0.0f;
            wsum += wv[k];
        }
        #pragma unroll
        for (int d = 1; d < 16; d <<= 1) wsum += __shfl_xor(wsum, d);

        const float inv = frcp(wsum + 1e-8f);
        #pragma unroll
        for (int k = 0; k < 3; ++k)
            if (k < ns) wgt[sub][h][sI[k]] = wv[k] * inv;
    }
    __syncthreads();

    const char* xbB = (const char*)(xbf + (size_t)b * LDIM * CDIM);
    const int cbyte = lt * 16;
    float a0=0,a1=0,a2=0,a3=0,a4=0,a5=0,a6=0,a7=0;

    #define GFMA(V, W) do { \
        a0 += (W) * u2f((V)[0] << 16); a1 += (W) * u2f((V)[0] & 0xffff0000u); \
        a2 += (W) * u2f((V)[1] << 16); a3 += (W) * u2f((V)[1] & 0xffff0000u); \
        a4 += (W) * u2f((V)[2] << 16); a5 += (W) * u2f((V)[2] & 0xffff0000u); \
        a6 += (W) * u2f((V)[3] << 16); a7 += (W) * u2f((V)[3] & 0xffff0000u); } while (0)

    int s = 0;
    for (; s + 4 <= SN; s += 4) {
        u32x4 v0 = *(const u32x4*)(xbB + boff[sub][s]     + cbyte);
        u32x4 v1 = *(const u32x4*)(xbB + boff[sub][s + 1] + cbyte);
        u32x4 v2 = *(const u32x4*)(xbB + boff[sub][s + 2] + cbyte);
        u32x4 v3 = *(const u32x4*)(xbB + boff[sub][s + 3] + cbyte);
        float w0 = wgt[sub][h][s],     w1 = wgt[sub][h][s + 1];
        float w2 = wgt[sub][h][s + 2], w3 = wgt[sub][h][s + 3];
        GFMA(v0, w0); GFMA(v1, w1); GFMA(v2, w2); GFMA(v3, w3);
    }
    for (; s < SN; ++s) {
        u32x4 v = *(const u32x4*)(xbB + boff[sub][s] + cbyte);
        float w = wgt[sub][h][s];
        GFMA(v, w);
    }
    #undef GFMA

    u16x8 o;
    o[0]=f2b(a0); o[1]=f2b(a1); o[2]=f2b(a2); o[3]=f2b(a3);
    o[4]=f2b(a4); o[5]=f2b(a5); o[6]=f2b(a6); o[7]=f2b(a7);
    *(u16x8*)(out + (size_t)t * CDIM + lt * 8) = o;
}

// ---------------------------------------------------------------------------
extern "C" void kernel_launch(void* const* d_in, const int* in_sizes, int n_in,
                              void* d_out, int out_size, void* d_ws, size_t ws_size,
                              hipStream_t stream)
{
    const float* x       = (const float*)d_in[0];
    const float* wave_w  = (const float*)d_in[1];
    const float* wave_b  = (const float*)d_in[2];
    const float* query_w = (const float*)d_in[3];
    const float* query_b = (const float*)d_in[4];
    const float* key_w   = (const float*)d_in[5];
    const float* out_w   = (const float*)d_in[6];
    const float* se1_w   = (const float*)d_in[7];
    const float* se1_b   = (const float*)d_in[8];
    const float* se2_w   = (const float*)d_in[9];
    const float* se2_b   = (const float*)d_in[10];

    char* wsb = (char*)d_ws;
    u16* q_bf    = (u16*)wsb;           wsb += (size_t)NTOK * 128 * 2;
    u16* x_bf    = (u16*)wsb;           wsb += (size_t)NTOK * CDIM * 2;
    u16* conv_bf = (u16*)wsb;           wsb += (size_t)NTOK * CDIM * 2;
    u16* tmp1_bf = (u16*)wsb;           wsb += (size_t)NTOK * 256 * 2;
    u16* g_bf    = (u16*)wsb;           wsb += (size_t)NTOK * CDIM * 2;
    u16* qw_bf   = (u16*)wsb;           wsb += (size_t)128 * CDIM * 2;
    u16* se1w_bf = (u16*)wsb;           wsb += (size_t)256 * CDIM * 2;
    u16* se2w_bf = (u16*)wsb;           wsb += (size_t)CDIM * 256 * 2;
    u16* outw_bf = (u16*)wsb;           wsb += (size_t)CDIM * CDIM * 2;
    float* wwT   = (float*)wsb;         wsb += (size_t)24 * CDIM * 4;
    float* part  = (float*)wsb;         wsb += (size_t)8 * NTOK * 24 * 4;

    // All weight preps in one launch
    transcast_all<<<1760, 256, 0, stream>>>(
        query_w, se1_w, se2_w, out_w, wave_w,
        qw_bf, se1w_bf, se2w_bf, outw_bf, wwT);

    // Wave projection: K-split partials (+fused xcast)
    wave_partial<<<8 * 128, 256, 0, stream>>>(x, wwT, x_bf, part);

    // QPROJ: silu(x @ query_w + b) -> q (bf16).  64x128 tile
    mfma_gemm<1, 2><<<dim3(NTOK / 64, 1), 256, 0, stream>>>(
        x_bf, qw_bf, query_b, nullptr, q_bf, NTOK, 128, CDIM);

    // Adaptive conv (+fused wave fixup) -> conv (bf16)
    adaptconv_kernel<<<NTOK / 2, 256, 0, stream>>>(
        x_bf, key_w, q_bf, part, wave_b, conv_bf);

    // SE1: silu(conv @ se1_w + b) -> tmp1 (bf16).  64x128 tile
    mfma_gemm<1, 2><<<dim3(NTOK / 64, 256 / 128), 256, 0, stream>>>(
        conv_bf, se1w_bf, se1_b, nullptr, tmp1_bf, NTOK, 256, CDIM);

    // SE2: sigmoid(tmp1 @ se2_w + b) * conv -> g (bf16)
    mfma_gemm<2, 0><<<dim3(NTOK / 128, CDIM / 128), 256, 0, stream>>>(
        tmp1_bf, se2w_bf, se2_b, conv_bf, g_bf, NTOK, CDIM, 256);

    // OUT: silu(g @ out_w) -> d_out (f32)
    mfma_gemm<3, 0><<<dim3(NTOK / 128, CDIM / 128), 256, 0, stream>>>(
        g_bf, outw_bf, nullptr, nullptr, d_out, NTOK, CDIM, CDIM);
}